// Round 7
// baseline (184.259 us; speedup 1.0000x reference)
//
#include <hip/hip_runtime.h>
#include <math.h>

#define LL 128
#define TT 11
#define NP 121            // T*T (y, y_prev) pairs
#define KK 7
#define NSLOT 8           // E-pane LDS ring slots
#define PANEF 1536        // floats per pane: [h=2][slot=192][4]

#define LOG2E 1.4426950408889634f
#define LN2   0.6931471805599453f

__device__ __forceinline__ float fast_exp2(float x) { return __builtin_amdgcn_exp2f(x); }
__device__ __forceinline__ float fast_log2(float x) { return __builtin_amdgcn_logf(x); }
#if __has_builtin(__builtin_amdgcn_rcpf)
__device__ __forceinline__ float fast_rcp(float x) { return __builtin_amdgcn_rcpf(x); }
#else
__device__ __forceinline__ float fast_rcp(float x) { return 1.0f / x; }
#endif
__device__ __forceinline__ float rfl(float x) {
    return __int_as_float(__builtin_amdgcn_readfirstlane(__float_as_int(x)));
}
__device__ __forceinline__ void cfence() { __builtin_amdgcn_wave_barrier(); }
#define VMWAIT42() asm volatile("s_waitcnt vmcnt(42)" ::: "memory")
#define VMWAIT21() asm volatile("s_waitcnt vmcnt(21)" ::: "memory")
#define VMWAIT0()  asm volatile("s_waitcnt vmcnt(0)"  ::: "memory")
#define LGKM0()    asm volatile("s_waitcnt lgkmcnt(0)" ::: "memory")

__device__ __forceinline__ void block_sync() {
    asm volatile("" ::: "memory");
    __builtin_amdgcn_s_barrier();
    asm volatile("" ::: "memory");
}

// ---------------------------------------------------------------------------
// Producer/consumer semi-CRF forward DP, v4: SHUFFLE-BASED phase 2.
//
// Round-6 post-mortem: 572 cyc/step, dominated by the sp LDS round-trip
// (write -> in-order DS pipe -> ~120cyc read latency -> sums) plus DS-pipe
// queueing of ~56 b128 ops/tick (consumer E reads + producer pane writes).
//
// v4 removes the round-trip entirely. Slot map: s = yp*16 + y (192 slots,
// y = s&15, yp = s>>4). Lane l owns slots {l, l+64, l+128}: all share
// y = l&15, with yp = (l>>4) + {0,4,8}. Per step:
//   phase 1: three 7-FMA dots s_m = sum_k E_m[k]*W_m[k]  (W_m = window for
//            row yp_m; three windows per lane, 21 regs)
//   phase 2: t = s0+s1+s2; t += shfl_xor(t,16); t += shfl_xor(t,32)
//            -> EVERY lane holds S(y=l&15). No LDS writes, no round-trip.
//   new rows: W_m[6] = S(yp_m)*r via ds_bpermute from lane yp_m (lane i<16
//            holds S(i)); r = rcp(S(0)) via readfirstlane (lane 0 holds S(0)).
// Invalid slots (y>10, yp>10) have E=0 everywhere -> contribute 0; S(11)=0
// feeds only nonexistent row 11 windows whose E=0. Masking identical to
// rounds 0-6 (select after exp2, j<0 and pair-validity).
//
// E pane layout [h][s][4]: h=0 holds k0..3, h=1 holds k4..6+pad; all reads
// and writes are stride-16B contiguous b128 (conflict-free). Pane = 6 KB,
// ring = 8 panes = 48 KB. Consumer triple-buffers (EA/EB/EC) with lead-2
// prefetch issued AFTER each step's shuffle chain (per-wave DS stream is
// in-order: chain ops first, prefetch behind).
//
// Producers (2 waves, odd/even panes): gathers are row-contiguous
// (offset = yp_m*11 + (l&15)); 21 loads/pane, 4-buffer (A..D) rotation,
// issue-before-conv with vmcnt(42) (63 outstanding max), publish via 6
// stride-16 ds_write_b128, lgkmcnt(0) before each barrier.
// Tick = 4 DP steps; 32 barriers per wave incl. B0.
// ---------------------------------------------------------------------------
__global__ __launch_bounds__(192, 1) void hscrf_pc4(const float* __restrict__ scores,
                                                    const int* __restrict__ mask,
                                                    float* __restrict__ out,
                                                    int n_batch)
{
    const int tid = threadIdx.x;
    const int l   = tid & 63;
    const int wid = tid >> 6;
    const int b   = blockIdx.x;
    if (b >= n_batch) return;

    __shared__ __align__(64) float ring[NSLOT][PANEF];   // 48 KB

    const float* sb = scores + (size_t)b * (size_t)(LL * (size_t)LL * NP);

    const int r = l >> 4;          // yp base (yp_m = r + 4m)
    const int c = l & 15;          // y of this lane's slots

    if (wid >= 1) {
        // ============ PRODUCERS (wave1: odd panes, wave2: even panes) ========
        const int pw = wid - 1;

        const bool vy  = (c <= 10);
        const bool vm2 = vy && (r <= 2);                  // yp=r+8 <= 10
        const int off0 = vy  ? (r * TT + c)       : 0;    // yp_0 = r
        const int off1 = vy  ? ((r + 4) * TT + c) : 0;    // yp_1 = r+4
        const int off2 = vm2 ? ((r + 8) * TT + c) : 0;    // yp_2 = r+8

        float A[3][KK], B[3][KK], C[3][KK], D[3][KK];     // 4-buffer rotation

        auto issueP = [&](int p, float (&g)[3][KK]) {
#pragma unroll
            for (int k = 0; k < KK; ++k) {
                const int j = p - KK + k; const int jc = j < 0 ? 0 : j;
                const float* sl = sb + ((size_t)jc * LL + (size_t)(p - 1)) * NP;
                g[0][k] = sl[off0];
                g[1][k] = sl[off1];
                g[2][k] = sl[off2];
            }
        };

        auto convP = [&](int p, const float (&g)[3][KK]) {
            const int slot = p & (NSLOT - 1);
            float4* b16 = (float4*)&ring[slot][0];
            float e0[KK], e1[KK], e2[KK];
#pragma unroll
            for (int k = 0; k < KK; ++k) {
                const bool okj = (p - KK + k) >= 0;       // j >= 0 mask
                const float t0 = fast_exp2(g[0][k] * LOG2E);
                const float t1 = fast_exp2(g[1][k] * LOG2E);
                const float t2 = fast_exp2(g[2][k] * LOG2E);
                e0[k] = (okj && vy)  ? t0 : 0.0f;
                e1[k] = (okj && vy)  ? t1 : 0.0f;
                e2[k] = (okj && vm2) ? t2 : 0.0f;
            }
            b16[l]             = make_float4(e0[0], e0[1], e0[2], e0[3]);
            b16[192 + l]       = make_float4(e0[4], e0[5], e0[6], 0.0f);
            b16[64 + l]        = make_float4(e1[0], e1[1], e1[2], e1[3]);
            b16[256 + l]       = make_float4(e1[4], e1[5], e1[6], 0.0f);
            b16[128 + l]       = make_float4(e2[0], e2[1], e2[2], e2[3]);
            b16[320 + l]       = make_float4(e2[4], e2[5], e2[6], 0.0f);
        };

        // Prologue: publish panes {1,3}+pw; leave {5,7}+pw in flight (C, D).
        issueP(1 + pw, A);
        issueP(3 + pw, B);                                // 42 outstanding
        VMWAIT21();                                       // A done
        convP(1 + pw, A);
        issueP(5 + pw, C);                                // B,C = 42
        VMWAIT21();                                       // B done
        convP(3 + pw, B);
        issueP(7 + pw, D);                                // C,D = 42
        LGKM0(); block_sync();                            // B0: panes 1..4 live

        // Ticks 1..30 (odd/even pairs). Odd t: conv C,D; even t: conv A,B.
        for (int t = 1; t <= 29; t += 2) {
            // odd tick t
            issueP(4 * t + 5 + pw, A);                    // C,D,A = 63
            VMWAIT42();                                   // C done
            convP(4 * t + 1 + pw, C);
            issueP(4 * t + 7 + pw, B);                    // D,A,B = 63
            VMWAIT42();                                   // D done
            convP(4 * t + 3 + pw, D);
            LGKM0(); block_sync();
            // even tick t+1
            issueP(4 * t + 9 + pw, C);                    // A,B,C = 63
            VMWAIT42();                                   // A done
            convP(4 * t + 5 + pw, A);
            issueP(4 * t + 11 + pw, D);                   // B,C,D = 63
            VMWAIT42();                                   // B done
            convP(4 * t + 7 + pw, B);
            LGKM0(); block_sync();
        }
        // Tick 31: drain; publish panes {125,127}+pw (in C, D).
        VMWAIT21();                                       // C done
        convP(125 + pw, C);
        VMWAIT0();                                        // D done
        convP(127 + pw, D);
        LGKM0(); block_sync();
        // Producers done: 32 barriers incl. B0 (matches consumer).
    } else {
        // ================= CONSUMER (pure DP chain, shuffle phase-2) =========
        const int mb = mask[b];
        const int r1s = r + 4, r2s = r + 8;               // bperm sources

        // Three windows: W_m[k] = normalized exp2(alpha2[j][yp_m]).
        // Start: alpha[0][10] = 0 (linear 1), others NEG (linear 0).
        float W0[KK], W1[KK], W2[KK];
#pragma unroll
        for (int k = 0; k < KK; ++k) { W0[k] = 0.0f; W1[k] = 0.0f; W2[k] = 0.0f; }
        W0[KK - 1] = (r     == 10) ? 1.0f : 0.0f;         // never (r<=3)
        W1[KK - 1] = (r + 4 == 10) ? 1.0f : 0.0f;
        W2[KK - 1] = (r + 8 == 10) ? 1.0f : 0.0f;

        float Cc = 0.0f;
        float savedS = 1.0f, savedC = 0.0f;

        struct F6 { float4 a0, a1, b0, b1, c0, c1; };
        F6 EA, EB, EC;

        auto readPane = [&](int p, F6& d) {
            const float4* b16 = (const float4*)&ring[p & (NSLOT - 1)][0];
            d.a0 = b16[l];        d.a1 = b16[192 + l];
            d.b0 = b16[64 + l];   d.b1 = b16[256 + l];
            d.c0 = b16[128 + l];  d.c1 = b16[320 + l];
        };

        auto step = [&](int i, const F6& E, F6* pf, int pfp) {
            // ---- phase 1: three 7-FMA dot trees (pure VALU) ----
            float u0 = fmaf(E.a0.x, W0[0], E.a0.y * W0[1]);
            float v0 = fmaf(E.a0.z, W0[2], E.a0.w * W0[3]);
            float w0 = fmaf(E.a1.x, W0[4], E.a1.y * W0[5]);
            float s0 = (u0 + v0) + fmaf(E.a1.z, W0[6], w0);
            float u1 = fmaf(E.b0.x, W1[0], E.b0.y * W1[1]);
            float v1 = fmaf(E.b0.z, W1[2], E.b0.w * W1[3]);
            float w1 = fmaf(E.b1.x, W1[4], E.b1.y * W1[5]);
            float s1 = (u1 + v1) + fmaf(E.b1.z, W1[6], w1);
            float u2 = fmaf(E.c0.x, W2[0], E.c0.y * W2[1]);
            float v2 = fmaf(E.c0.z, W2[2], E.c0.w * W2[3]);
            float w2 = fmaf(E.c1.x, W2[4], E.c1.y * W2[5]);
            float s2 = (u2 + v2) + fmaf(E.c1.z, W2[6], w2);

            // ---- phase 2: cross-lane reduction over yp (no LDS round-trip) --
            float t = (s0 + s1) + s2;                     // yp = r, r+4, r+8
            t += __shfl_xor(t, 16);                       // + yp base r^1
            t += __shfl_xor(t, 32);                       // + yp base r^2
            // t = S(y = l&15) in every lane.

            // new rows: S(yp_m) from lane yp_m (lane i<16 holds S(i))
            const float n0 = __shfl(t, r);
            const float n1 = __shfl(t, r1s);
            const float n2 = __shfl(t, r2s);

            cfence();                      // DS order: shuffles before prefetch
            if (pf) readPane(pfp, *pf);    // lead-2 prefetch (off-chain)
            cfence();

            const float s0u = rfl(t);                     // S(0) from lane 0
            const float rr = fast_rcp(s0u);

            savedS = (i == mb) ? t  : savedS;             // lane 9 keeps S(9)
            savedC = (i == mb) ? Cc : savedC;
            Cc += fast_log2(s0u);                         // off-chain

#pragma unroll
            for (int k = 0; k < KK - 1; ++k) {
                W0[k] = W0[k + 1] * rr;
                W1[k] = W1[k + 1] * rr;
                W2[k] = W2[k + 1] * rr;
            }
            W0[KK - 1] = n0 * rr;
            W1[KK - 1] = n1 * rr;
            W2[KK - 1] = n2 * rr;
        };

        __builtin_amdgcn_s_setprio(1);
        block_sync();                                     // B0: panes 1..4 ready

        for (int t = 1; t <= 32; ++t) {
            const int p0 = 4 * t - 3;
            readPane(p0, EA);
            readPane(p0 + 1, EB);
            step(p0,     EA, &EC, p0 + 2);                // prefetch same-tick panes
            step(p0 + 1, EB, &EA, p0 + 3);                // (published last tick)
            step(p0 + 2, EC, nullptr, 0);
            step(p0 + 3, EA, nullptr, 0);
            if (t < 32) block_sync();                     // 31 tick barriers
        }

        if (l == 9) {                                     // lane 9: y == stop_id = 9
            atomicAdd(out, (savedC + fast_log2(savedS)) * LN2);
        }
    }
}

extern "C" void kernel_launch(void* const* d_in, const int* in_sizes, int n_in,
                              void* d_out, int out_size, void* d_ws, size_t ws_size,
                              hipStream_t stream) {
    const float* scores = (const float*)d_in[0];
    const int*   mask   = (const int*)d_in[1];
    float* out = (float*)d_out;
    const int B = in_sizes[1];   // 16

    hipMemsetAsync(out, 0, sizeof(float) * out_size, stream);

    (void)d_ws; (void)ws_size;   // unused (ws poison is unconditional harness cost)

    hscrf_pc4<<<B, 192, 0, stream>>>(scores, mask, out, B);
}